// Round 1
// baseline (1545.773 us; speedup 1.0000x reference)
//
#include <hip/hip_runtime.h>
#include <hip/hip_bf16.h>
#include <stdint.h>

#define NS 32768
#define NXD 64
#define KD 16
#define ED 32
#define DYD 32

typedef __attribute__((ext_vector_type(8))) short short8;
typedef __attribute__((ext_vector_type(4))) float f32x4;

__device__ __forceinline__ void gl_lds16(const void* g, void* s) {
  __builtin_amdgcn_global_load_lds(
      (const __attribute__((address_space(1))) void*)(uintptr_t)g,
      (__attribute__((address_space(3))) void*)(uint32_t)(uintptr_t)s,
      16, 0, 0);
}

// fast tanh: 1 - 2/(e^{2v}+1).  v_exp + v_rcp; saturates correctly at +-inf.
__device__ __forceinline__ float tanh_fast(float v) {
  float ex = __expf(2.f * v);
  return 1.f - __fdividef(2.f, ex + 1.f);
}

// fp32 -> bf16 bits, round-to-nearest-even
__device__ __forceinline__ unsigned short f2bf(float f) {
  uint32_t u = __float_as_uint(f);
  return (unsigned short)((u + 0x7fffu + ((u >> 16) & 1u)) >> 16);
}

// ---------------------------------------------------------------- K0: W12T
// W12T[col=o*64+i][ke=k*32+e] = W1[k,i,e] * W2[k,e,o]   (4096 x 512, bf16)
__global__ __launch_bounds__(256) void prep_w12(
    const float* __restrict__ W1, const float* __restrict__ W2,
    __hip_bfloat16* __restrict__ W12T) {
  int idx = blockIdx.x * 256 + threadIdx.x;        // 0 .. 2M-1
  int col = idx >> 9;
  int ke  = idx & 511;
  int o = col >> 6, i = col & 63;
  int k = ke >> 5,  e = ke & 31;
  float v = W1[k * 2048 + i * 32 + e] * W2[k * 2048 + e * 64 + o];
  W12T[idx] = __float2bfloat16(v);
}

// --------------------------------------------------------------- K1: branch
// per sample: y_norm -> weights (softplus) -> wts[n][16]
//             bias net -> zout[n][o] = x + bias + w@b2
__global__ __launch_bounds__(256) void branch_kernel(
    const float* __restrict__ x, const float* __restrict__ y,
    const float* __restrict__ b2,
    const float* __restrict__ Wb1, const float* __restrict__ bb1,
    const float* __restrict__ Wb2, const float* __restrict__ bb2,
    const float* __restrict__ Wc1, const float* __restrict__ bc1,
    const float* __restrict__ Wc2, const float* __restrict__ bc2,
    const float* __restrict__ meanp, const float* __restrict__ varp,
    float* __restrict__ wts, float* __restrict__ zout) {
  int n = blockIdx.x * 256 + threadIdx.x;
  float yn[DYD];
#pragma unroll
  for (int d = 0; d < DYD; d++) {
    float t = (y[n * DYD + d] - meanp[d]) / sqrtf(varp[d]);
    yn[d] = fminf(fmaxf(t, -10.f), 10.f);
  }
  float t1[64];
#pragma unroll
  for (int u = 0; u < 64; u++) {
    float a = bb1[u];
#pragma unroll
    for (int d = 0; d < DYD; d++) a += yn[d] * Wb1[d * 64 + u];
    t1[u] = fmaxf(a, 0.f);
  }
  float w[KD];
#pragma unroll
  for (int k = 0; k < KD; k++) {
    float a = bb2[k];
#pragma unroll
    for (int u = 0; u < 64; u++) a += t1[u] * Wb2[u * KD + k];
    w[k] = (a > 20.f) ? a : log1pf(expf(a));
    wts[n * KD + k] = w[k];
  }
  float t2[16];
#pragma unroll
  for (int j = 0; j < 16; j++) {
    float a = bc1[j];
#pragma unroll
    for (int d = 0; d < DYD; d++) a += yn[d] * Wc1[d * 16 + j];
    t2[j] = fmaxf(a, 0.f);
  }
#pragma unroll
  for (int o = 0; o < NXD; o++) {
    float a = bc2[o] + x[n * NXD + o];
#pragma unroll
    for (int j = 0; j < 16; j++) a += t2[j] * Wc2[j * 64 + o];
#pragma unroll
    for (int k = 0; k < KD; k++) a += w[k] * b2[k * 64 + o];
    zout[n * NXD + o] = a;
  }
}

// ----------------------------------------------------------------- K2: MoE
// Register-blocked fp32 restructure.
// Phase 1: thread owns 2 samples x 8 contiguous ke (one k).  Per i:
//   1 broadcast ds_read_b64 (x pair) + 2 global dwordx4 (W1, contiguous in e)
//   + 16 independent FMAs.  No per-thread x array -> no scratch.
// Phase 2: thread owns (sample, 4 o, half of ke); f32x4 P (LDS broadcast) +
//   dwordx4 W2 rows; partial sums combined through reused xsI LDS.
__global__ __launch_bounds__(256) void moe_kernel(
    const float* __restrict__ x, const float* __restrict__ W1,
    const float* __restrict__ b1, const float* __restrict__ W2,
    const float* __restrict__ wts,
    __hip_bfloat16* __restrict__ Mb, float* __restrict__ zout) {
  __shared__ __align__(16) float xsI[512];      // [i][s] interleaved, 2 KB
  __shared__ __align__(16) float Pl[8 * 512];   // 16 KB
  __shared__ float wl[128];                     // 0.5 KB
  const int t = threadIdx.x;
  const int n0 = blockIdx.x * 8;

  // stage x interleaved: xsI[i*8+s] = x[n0+s][i]
#pragma unroll
  for (int r = 0; r < 2; r++) {
    int idx = t + r * 256;
    xsI[idx] = x[(size_t)(n0 + (idx & 7)) * 64 + (idx >> 3)];
  }
  if (t < 128) wl[t] = wts[n0 * 16 + t];
  __syncthreads();

  // ---- phase 1: pre = x @ W1 + b1 (16 accumulators, 2 samples x 8 ke)
  const int c = t & 63;          // ke-chunk: ke0 = c*8 lies inside one k
  const int p = t >> 6;          // sample pair: samples 2p, 2p+1
  const int ke0 = c * 8;
  const int k = c >> 2;
  f32x4 bA = *(const f32x4*)(b1 + ke0);
  f32x4 bB = *(const f32x4*)(b1 + ke0 + 4);
  f32x4 a0A = bA, a0B = bB, a1A = bA, a1B = bB;
  const float* w1p = W1 + k * 2048 + (c & 3) * 8;
  const float* xp = xsI + 2 * p;
#pragma unroll 4
  for (int i = 0; i < 64; i++) {
    float2 xv = *(const float2*)(xp + i * 8);          // broadcast b64
    f32x4 wA = *(const f32x4*)(w1p + i * 32);
    f32x4 wB = *(const f32x4*)(w1p + i * 32 + 4);
    a0A += xv.x * wA; a0B += xv.x * wB;
    a1A += xv.y * wA; a1B += xv.y * wB;
  }

  const int s0 = 2 * p;
  const float wk0 = wl[s0 * 16 + k];
  const float wk1 = wl[s0 * 16 + 16 + k];
  short8 m0, m1;
  f32x4 p0A, p0B, p1A, p1B;
#pragma unroll
  for (int q = 0; q < 4; q++) {
    float h;
    h = tanh_fast(a0A[q]); m0[q]     = (short)f2bf(wk0 * (1.f - h * h)); p0A[q] = wk0 * h;
    h = tanh_fast(a0B[q]); m0[4 + q] = (short)f2bf(wk0 * (1.f - h * h)); p0B[q] = wk0 * h;
    h = tanh_fast(a1A[q]); m1[q]     = (short)f2bf(wk1 * (1.f - h * h)); p1A[q] = wk1 * h;
    h = tanh_fast(a1B[q]); m1[4 + q] = (short)f2bf(wk1 * (1.f - h * h)); p1B[q] = wk1 * h;
  }
  *(short8*)(Mb + (size_t)(n0 + s0) * 512 + ke0) = m0;
  *(short8*)(Mb + (size_t)(n0 + s0 + 1) * 512 + ke0) = m1;
  *(f32x4*)(Pl + s0 * 512 + ke0) = p0A;
  *(f32x4*)(Pl + s0 * 512 + ke0 + 4) = p0B;
  *(f32x4*)(Pl + (s0 + 1) * 512 + ke0) = p1A;
  *(f32x4*)(Pl + (s0 + 1) * 512 + ke0 + 4) = p1B;
  __syncthreads();

  // ---- phase 2: z += P @ W2.  thread = (sample sm, 4 outputs, ke-half kh)
  const int og = t & 15, sm = (t >> 4) & 7, kh = t >> 7;
  const float* pbase = Pl + sm * 512 + kh * 256;
  const float* w2base = W2 + kh * 256 * 64 + og * 4;
  f32x4 za = {0.f, 0.f, 0.f, 0.f}, zb = {0.f, 0.f, 0.f, 0.f};
#pragma unroll 2
  for (int kk = 0; kk < 256; kk += 4) {
    f32x4 pv = *(const f32x4*)(pbase + kk);            // 16-lane broadcast
    za += pv[0] * *(const f32x4*)(w2base + (kk + 0) * 64);
    zb += pv[1] * *(const f32x4*)(w2base + (kk + 1) * 64);
    za += pv[2] * *(const f32x4*)(w2base + (kk + 2) * 64);
    zb += pv[3] * *(const f32x4*)(w2base + (kk + 3) * 64);
  }
  f32x4 zacc = za + zb;
  float* zp = (float*)xsI;   // xsI is dead; reuse 2 KB as partial-sum buffer
  if (kh) { *(f32x4*)(zp + (t - 128) * 4) = zacc; }
  __syncthreads();
  if (!kh) {
    f32x4 oth = *(const f32x4*)(zp + t * 4);
    float* zg = zout + (size_t)(n0 + sm) * 64 + og * 4;
    f32x4 zv = *(const f32x4*)zg;                      // RMW (z from branch)
    zv += zacc + oth;
    *(f32x4*)zg = zv;
  }
}

// ---------------------------------------------------------------- K3: GEMM
// C[32768][4096] = A[32768][512] * B^T, B = W12T[4096][512]; C += I on col%65==0
#define BM 128
#define BN 128
#define BK 32
__global__ __launch_bounds__(256) void jac_gemm(
    const __hip_bfloat16* __restrict__ Abf, const __hip_bfloat16* __restrict__ Bbf,
    float* __restrict__ C) {
  __shared__ __align__(16) short As[BM * BK];  // [row][k], 8 KB
  __shared__ __align__(16) short Bs[BN * BK];  // [col][k], 8 KB

  const int tid = threadIdx.x;
  const int wave = tid >> 6;
  const int lane = tid & 63;
  const int row0 = blockIdx.y * BM;
  const int col0 = blockIdx.x * BN;

  const int srow = wave * 32 + (lane >> 2);  // +16 for round 1
  const int skc = (lane & 3) * 8;            // k-element offset

  const short* Ag = (const short*)Abf;
  const short* Bg = (const short*)Bbf;

  f32x4 acc[4][4];
#pragma unroll
  for (int i = 0; i < 4; i++)
#pragma unroll
    for (int j = 0; j < 4; j++) acc[i][j] = (f32x4){0.f, 0.f, 0.f, 0.f};

  const int wm = wave >> 1, wn = wave & 1;
  const int lr = lane & 15;
  const int quad = lane >> 4;

  for (int k0 = 0; k0 < 512; k0 += BK) {
    const short* gA0 = Ag + (size_t)(row0 + srow) * 512 + k0 + skc;
    const short* gB0 = Bg + (size_t)(col0 + srow) * 512 + k0 + skc;
    gl_lds16(gA0, &As[srow * 32 + skc]);
    gl_lds16(gA0 + 16 * 512, &As[(srow + 16) * 32 + skc]);
    gl_lds16(gB0, &Bs[srow * 32 + skc]);
    gl_lds16(gB0 + 16 * 512, &Bs[(srow + 16) * 32 + skc]);
    __syncthreads();  // compiler drains vmcnt before s_barrier

    short8 af[4], bf[4];
#pragma unroll
    for (int mi = 0; mi < 4; mi++)
      af[mi] = *(const short8*)&As[(wm * 64 + mi * 16 + lr) * 32 + quad * 8];
#pragma unroll
    for (int ni = 0; ni < 4; ni++)
      bf[ni] = *(const short8*)&Bs[(wn * 64 + ni * 16 + lr) * 32 + quad * 8];
#pragma unroll
    for (int mi = 0; mi < 4; mi++)
#pragma unroll
      for (int ni = 0; ni < 4; ni++)
        acc[mi][ni] = __builtin_amdgcn_mfma_f32_16x16x32_bf16(af[mi], bf[ni], acc[mi][ni], 0, 0, 0);
    __syncthreads();
  }

#pragma unroll
  for (int mi = 0; mi < 4; mi++) {
#pragma unroll
    for (int r = 0; r < 4; r++) {
      int row = row0 + wm * 64 + mi * 16 + quad * 4 + r;
      float* Crow = C + (size_t)row * 4096 + col0 + wn * 64;
#pragma unroll
      for (int ni = 0; ni < 4; ni++) {
        int c = ni * 16 + lr;
        int gc = col0 + wn * 64 + c;
        float v = acc[mi][ni][r];
        if ((gc & 63) == (gc >> 6)) v += 1.0f;  // + I(o==i)
        Crow[c] = v;
      }
    }
  }
}

extern "C" void kernel_launch(void* const* d_in, const int* in_sizes, int n_in,
                              void* d_out, int out_size, void* d_ws, size_t ws_size,
                              hipStream_t stream) {
  const float* x = (const float*)d_in[0];
  const float* y = (const float*)d_in[1];
  const float* W1 = (const float*)d_in[2];
  const float* b1 = (const float*)d_in[3];
  const float* W2 = (const float*)d_in[4];
  const float* b2 = (const float*)d_in[5];
  const float* Wb1 = (const float*)d_in[6];
  const float* bb1 = (const float*)d_in[7];
  const float* Wb2 = (const float*)d_in[8];
  const float* bb2 = (const float*)d_in[9];
  const float* Wc1 = (const float*)d_in[10];
  const float* bc1 = (const float*)d_in[11];
  const float* Wc2 = (const float*)d_in[12];
  const float* bc2 = (const float*)d_in[13];
  const float* meanp = (const float*)d_in[14];
  const float* varp = (const float*)d_in[15];

  float* z = (float*)d_out;
  float* jac = z + (size_t)NS * NXD;

  char* ws = (char*)d_ws;
  __hip_bfloat16* W12T = (__hip_bfloat16*)ws;                        // 4 MB
  __hip_bfloat16* Mb = (__hip_bfloat16*)(ws + (4ull << 20));         // 32 MB
  float* wts = (float*)(ws + (36ull << 20));                         // 2 MB

  prep_w12<<<dim3(8192), dim3(256), 0, stream>>>(W1, W2, W12T);
  branch_kernel<<<dim3(128), dim3(256), 0, stream>>>(
      x, y, b2, Wb1, bb1, Wb2, bb2, Wc1, bc1, Wc2, bc2, meanp, varp, wts, z);
  moe_kernel<<<dim3(4096), dim3(256), 0, stream>>>(x, W1, b1, W2, wts, Mb, z);
  jac_gemm<<<dim3(32, 256), dim3(256), 0, stream>>>(Mb, W12T, jac);
}

// Round 2
// 949.667 us; speedup vs baseline: 1.6277x; 1.6277x over previous
//
#include <hip/hip_runtime.h>
#include <hip/hip_bf16.h>
#include <stdint.h>

#define NS 32768
#define NXD 64
#define KD 16
#define ED 32
#define DYD 32

typedef __attribute__((ext_vector_type(8))) short short8;
typedef __attribute__((ext_vector_type(4))) float f32x4;

__device__ __forceinline__ void gl_lds16(const void* g, void* s) {
  __builtin_amdgcn_global_load_lds(
      (const __attribute__((address_space(1))) void*)(uintptr_t)g,
      (__attribute__((address_space(3))) void*)(uint32_t)(uintptr_t)s,
      16, 0, 0);
}

// fast tanh: 1 - 2/(e^{2v}+1).  v_exp + v_rcp; saturates correctly at +-inf.
__device__ __forceinline__ float tanh_fast(float v) {
  float ex = __expf(2.f * v);
  return 1.f - __fdividef(2.f, ex + 1.f);
}

// fp32 -> bf16 bits, round-to-nearest-even
__device__ __forceinline__ unsigned short f2bf(float f) {
  uint32_t u = __float_as_uint(f);
  return (unsigned short)((u + 0x7fffu + ((u >> 16) & 1u)) >> 16);
}

// ---------------------------------------------------------------- K0: W12T
// W12T[col=o*64+i][ke=k*32+e] = W1[k,i,e] * W2[k,e,o]   (4096 x 512, bf16)
__global__ __launch_bounds__(256) void prep_w12(
    const float* __restrict__ W1, const float* __restrict__ W2,
    __hip_bfloat16* __restrict__ W12T) {
  int idx = blockIdx.x * 256 + threadIdx.x;        // 0 .. 2M-1
  int col = idx >> 9;
  int ke  = idx & 511;
  int o = col >> 6, i = col & 63;
  int k = ke >> 5,  e = ke & 31;
  float v = W1[k * 2048 + i * 32 + e] * W2[k * 2048 + e * 64 + o];
  W12T[idx] = __float2bfloat16(v);
}

// ------------------------------------------------------- K0b: branch weights
// Transposed copies for contiguous f32x4 reads in branch_kernel.
// bw layout (floats): [0) Wb1T[64][32]  [2048) Wc1T[16][32]
//                     [2560) Wc2T[64][16]  [3584) b2T[64][16]   (18 KB)
__global__ __launch_bounds__(256) void prep_branchw(
    const float* __restrict__ Wb1, const float* __restrict__ Wc1,
    const float* __restrict__ Wc2, const float* __restrict__ b2,
    float* __restrict__ bw) {
  int t = threadIdx.x;
  for (int i = t; i < 2048; i += 256) { int u = i >> 5, d = i & 31; bw[i] = Wb1[d * 64 + u]; }
  for (int i = t; i < 512;  i += 256) { int j = i >> 5, d = i & 31; bw[2048 + i] = Wc1[d * 16 + j]; }
  for (int i = t; i < 1024; i += 256) { int o = i >> 4, j = i & 15; bw[2560 + i] = Wc2[j * 64 + o]; }
  for (int i = t; i < 1024; i += 256) { int o = i >> 4, k = i & 15; bw[3584 + i] = b2[k * 64 + o]; }
}

// --------------------------------------------------------------- K1: branch
// 4 threads per sample (quad q owns 16 u's / 16 o's).  Loop-swap removes the
// t1[64] scratch array; w partials combined via 2x shfl_xor within the quad.
// Grid 512 x 256 -> 2048 waves (2/SIMD), all CUs covered.
__global__ __launch_bounds__(256) void branch_kernel(
    const float* __restrict__ x, const float* __restrict__ y,
    const float* __restrict__ bw, const float* __restrict__ Wb2,
    const float* __restrict__ bb1, const float* __restrict__ bb2,
    const float* __restrict__ bc1, const float* __restrict__ bc2,
    const float* __restrict__ meanp, const float* __restrict__ varp,
    float* __restrict__ wts, float* __restrict__ zout) {
  const int t = threadIdx.x;
  const int q = t & 3;
  const int s = t >> 2;
  const int n = blockIdx.x * 64 + s;

  const float* Wb1T = bw;            // [64][32]
  const float* Wc1T = bw + 2048;     // [16][32]
  const float* Wc2T = bw + 2560;     // [64][16]
  const float* b2T  = bw + 3584;     // [64][16]

  // y-normalize, all 32 dims in registers
  float yn[32];
#pragma unroll
  for (int d4 = 0; d4 < 8; d4++) {
    f32x4 v = *(const f32x4*)(y + (size_t)n * 32 + d4 * 4);
#pragma unroll
    for (int c = 0; c < 4; c++) {
      int d = d4 * 4 + c;
      float tv = (v[c] - meanp[d]) / sqrtf(varp[d]);
      yn[d] = fminf(fmaxf(tv, -10.f), 10.f);
    }
  }

  // layer 1 partial over u in [q*16, q*16+16); t1[u] consumed immediately
  float pw[16];
#pragma unroll
  for (int k = 0; k < 16; k++) pw[k] = 0.f;
#pragma unroll
  for (int uu = 0; uu < 16; uu++) {
    int u = q * 16 + uu;
    float a = bb1[u];
#pragma unroll
    for (int d4 = 0; d4 < 8; d4++) {
      f32x4 wv = *(const f32x4*)(Wb1T + u * 32 + d4 * 4);
      a += yn[d4 * 4 + 0] * wv[0] + yn[d4 * 4 + 1] * wv[1] +
           yn[d4 * 4 + 2] * wv[2] + yn[d4 * 4 + 3] * wv[3];
    }
    a = fmaxf(a, 0.f);
#pragma unroll
    for (int k4 = 0; k4 < 4; k4++) {
      f32x4 wb = *(const f32x4*)(Wb2 + u * 16 + k4 * 4);
#pragma unroll
      for (int c = 0; c < 4; c++) pw[k4 * 4 + c] += a * wb[c];
    }
  }

  // quad-combine + softplus
  float w[16];
#pragma unroll
  for (int k = 0; k < 16; k++) {
    float v = pw[k];
    v += __shfl_xor(v, 1);
    v += __shfl_xor(v, 2);
    v += bb2[k];
    w[k] = (v > 20.f) ? v : log1pf(expf(v));
  }

  // wts write: quad thread q writes w[q*4 .. q*4+4)  (static indexing only)
  {
    f32x4 wq;
    if (q == 0)      wq = (f32x4){w[0], w[1], w[2], w[3]};
    else if (q == 1) wq = (f32x4){w[4], w[5], w[6], w[7]};
    else if (q == 2) wq = (f32x4){w[8], w[9], w[10], w[11]};
    else             wq = (f32x4){w[12], w[13], w[14], w[15]};
    *(f32x4*)(wts + (size_t)n * 16 + q * 4) = wq;
  }

  // t2 (full 16 per thread)
  float t2[16];
#pragma unroll
  for (int j = 0; j < 16; j++) {
    float a = bc1[j];
#pragma unroll
    for (int d4 = 0; d4 < 8; d4++) {
      f32x4 wv = *(const f32x4*)(Wc1T + j * 32 + d4 * 4);
      a += yn[d4 * 4 + 0] * wv[0] + yn[d4 * 4 + 1] * wv[1] +
           yn[d4 * 4 + 2] * wv[2] + yn[d4 * 4 + 3] * wv[3];
    }
    t2[j] = fmaxf(a, 0.f);
  }

  // outputs: o in [q*16, q*16+16)
  const float* xp = x + (size_t)n * 64 + q * 16;
  float* zp = zout + (size_t)n * 64 + q * 16;
#pragma unroll
  for (int oo = 0; oo < 16; oo += 4) {
    f32x4 xv = *(const f32x4*)(xp + oo);
    f32x4 zv;
#pragma unroll
    for (int c = 0; c < 4; c++) {
      int o = q * 16 + oo + c;
      float a = bc2[o] + xv[c];
      const f32x4* wc = (const f32x4*)(Wc2T + o * 16);
      const f32x4* bt = (const f32x4*)(b2T + o * 16);
#pragma unroll
      for (int j4 = 0; j4 < 4; j4++) {
        f32x4 cv = wc[j4];
        a += t2[j4 * 4 + 0] * cv[0] + t2[j4 * 4 + 1] * cv[1] +
             t2[j4 * 4 + 2] * cv[2] + t2[j4 * 4 + 3] * cv[3];
      }
#pragma unroll
      for (int k4 = 0; k4 < 4; k4++) {
        f32x4 bv = bt[k4];
        a += w[k4 * 4 + 0] * bv[0] + w[k4 * 4 + 1] * bv[1] +
             w[k4 * 4 + 2] * bv[2] + w[k4 * 4 + 3] * bv[3];
      }
      zv[c] = a;
    }
    *(f32x4*)(zp + oo) = zv;
  }
}

// ----------------------------------------------------------------- K2: MoE
// Register-blocked fp32 restructure (unchanged from round 1).
__global__ __launch_bounds__(256) void moe_kernel(
    const float* __restrict__ x, const float* __restrict__ W1,
    const float* __restrict__ b1, const float* __restrict__ W2,
    const float* __restrict__ wts,
    __hip_bfloat16* __restrict__ Mb, float* __restrict__ zout) {
  __shared__ __align__(16) float xsI[512];      // [i][s] interleaved, 2 KB
  __shared__ __align__(16) float Pl[8 * 512];   // 16 KB
  __shared__ float wl[128];                     // 0.5 KB
  const int t = threadIdx.x;
  const int n0 = blockIdx.x * 8;

#pragma unroll
  for (int r = 0; r < 2; r++) {
    int idx = t + r * 256;
    xsI[idx] = x[(size_t)(n0 + (idx & 7)) * 64 + (idx >> 3)];
  }
  if (t < 128) wl[t] = wts[n0 * 16 + t];
  __syncthreads();

  const int c = t & 63;
  const int p = t >> 6;
  const int ke0 = c * 8;
  const int k = c >> 2;
  f32x4 bA = *(const f32x4*)(b1 + ke0);
  f32x4 bB = *(const f32x4*)(b1 + ke0 + 4);
  f32x4 a0A = bA, a0B = bB, a1A = bA, a1B = bB;
  const float* w1p = W1 + k * 2048 + (c & 3) * 8;
  const float* xp = xsI + 2 * p;
#pragma unroll 4
  for (int i = 0; i < 64; i++) {
    float2 xv = *(const float2*)(xp + i * 8);
    f32x4 wA = *(const f32x4*)(w1p + i * 32);
    f32x4 wB = *(const f32x4*)(w1p + i * 32 + 4);
    a0A += xv.x * wA; a0B += xv.x * wB;
    a1A += xv.y * wA; a1B += xv.y * wB;
  }

  const int s0 = 2 * p;
  const float wk0 = wl[s0 * 16 + k];
  const float wk1 = wl[s0 * 16 + 16 + k];
  short8 m0, m1;
  f32x4 p0A, p0B, p1A, p1B;
#pragma unroll
  for (int q = 0; q < 4; q++) {
    float h;
    h = tanh_fast(a0A[q]); m0[q]     = (short)f2bf(wk0 * (1.f - h * h)); p0A[q] = wk0 * h;
    h = tanh_fast(a0B[q]); m0[4 + q] = (short)f2bf(wk0 * (1.f - h * h)); p0B[q] = wk0 * h;
    h = tanh_fast(a1A[q]); m1[q]     = (short)f2bf(wk1 * (1.f - h * h)); p1A[q] = wk1 * h;
    h = tanh_fast(a1B[q]); m1[4 + q] = (short)f2bf(wk1 * (1.f - h * h)); p1B[q] = wk1 * h;
  }
  *(short8*)(Mb + (size_t)(n0 + s0) * 512 + ke0) = m0;
  *(short8*)(Mb + (size_t)(n0 + s0 + 1) * 512 + ke0) = m1;
  *(f32x4*)(Pl + s0 * 512 + ke0) = p0A;
  *(f32x4*)(Pl + s0 * 512 + ke0 + 4) = p0B;
  *(f32x4*)(Pl + (s0 + 1) * 512 + ke0) = p1A;
  *(f32x4*)(Pl + (s0 + 1) * 512 + ke0 + 4) = p1B;
  __syncthreads();

  const int og = t & 15, sm = (t >> 4) & 7, kh = t >> 7;
  const float* pbase = Pl + sm * 512 + kh * 256;
  const float* w2base = W2 + kh * 256 * 64 + og * 4;
  f32x4 za = {0.f, 0.f, 0.f, 0.f}, zb = {0.f, 0.f, 0.f, 0.f};
#pragma unroll 2
  for (int kk = 0; kk < 256; kk += 4) {
    f32x4 pv = *(const f32x4*)(pbase + kk);
    za += pv[0] * *(const f32x4*)(w2base + (kk + 0) * 64);
    zb += pv[1] * *(const f32x4*)(w2base + (kk + 1) * 64);
    za += pv[2] * *(const f32x4*)(w2base + (kk + 2) * 64);
    zb += pv[3] * *(const f32x4*)(w2base + (kk + 3) * 64);
  }
  f32x4 zacc = za + zb;
  float* zp = (float*)xsI;
  if (kh) { *(f32x4*)(zp + (t - 128) * 4) = zacc; }
  __syncthreads();
  if (!kh) {
    f32x4 oth = *(const f32x4*)(zp + t * 4);
    float* zg = zout + (size_t)(n0 + sm) * 64 + og * 4;
    f32x4 zv = *(const f32x4*)zg;
    zv += zacc + oth;
    *(f32x4*)zg = zv;
  }
}

// ---------------------------------------------------------------- K3: GEMM
// C[32768][4096] = A[32768][512] * B^T, B = W12T[4096][512]; C += I on col%65==0
#define BM 128
#define BN 128
#define BK 32
__global__ __launch_bounds__(256) void jac_gemm(
    const __hip_bfloat16* __restrict__ Abf, const __hip_bfloat16* __restrict__ Bbf,
    float* __restrict__ C) {
  __shared__ __align__(16) short As[BM * BK];  // [row][k], 8 KB
  __shared__ __align__(16) short Bs[BN * BK];  // [col][k], 8 KB

  const int tid = threadIdx.x;
  const int wave = tid >> 6;
  const int lane = tid & 63;
  const int row0 = blockIdx.y * BM;
  const int col0 = blockIdx.x * BN;

  const int srow = wave * 32 + (lane >> 2);
  const int skc = (lane & 3) * 8;

  const short* Ag = (const short*)Abf;
  const short* Bg = (const short*)Bbf;

  f32x4 acc[4][4];
#pragma unroll
  for (int i = 0; i < 4; i++)
#pragma unroll
    for (int j = 0; j < 4; j++) acc[i][j] = (f32x4){0.f, 0.f, 0.f, 0.f};

  const int wm = wave >> 1, wn = wave & 1;
  const int lr = lane & 15;
  const int quad = lane >> 4;

  for (int k0 = 0; k0 < 512; k0 += BK) {
    const short* gA0 = Ag + (size_t)(row0 + srow) * 512 + k0 + skc;
    const short* gB0 = Bg + (size_t)(col0 + srow) * 512 + k0 + skc;
    gl_lds16(gA0, &As[srow * 32 + skc]);
    gl_lds16(gA0 + 16 * 512, &As[(srow + 16) * 32 + skc]);
    gl_lds16(gB0, &Bs[srow * 32 + skc]);
    gl_lds16(gB0 + 16 * 512, &Bs[(srow + 16) * 32 + skc]);
    __syncthreads();

    short8 af[4], bf[4];
#pragma unroll
    for (int mi = 0; mi < 4; mi++)
      af[mi] = *(const short8*)&As[(wm * 64 + mi * 16 + lr) * 32 + quad * 8];
#pragma unroll
    for (int ni = 0; ni < 4; ni++)
      bf[ni] = *(const short8*)&Bs[(wn * 64 + ni * 16 + lr) * 32 + quad * 8];
#pragma unroll
    for (int mi = 0; mi < 4; mi++)
#pragma unroll
      for (int ni = 0; ni < 4; ni++)
        acc[mi][ni] = __builtin_amdgcn_mfma_f32_16x16x32_bf16(af[mi], bf[ni], acc[mi][ni], 0, 0, 0);
    __syncthreads();
  }

#pragma unroll
  for (int mi = 0; mi < 4; mi++) {
#pragma unroll
    for (int r = 0; r < 4; r++) {
      int row = row0 + wm * 64 + mi * 16 + quad * 4 + r;
      float* Crow = C + (size_t)row * 4096 + col0 + wn * 64;
#pragma unroll
      for (int ni = 0; ni < 4; ni++) {
        int c = ni * 16 + lr;
        int gc = col0 + wn * 64 + c;
        float v = acc[mi][ni][r];
        if ((gc & 63) == (gc >> 6)) v += 1.0f;  // + I(o==i)
        Crow[c] = v;
      }
    }
  }
}

extern "C" void kernel_launch(void* const* d_in, const int* in_sizes, int n_in,
                              void* d_out, int out_size, void* d_ws, size_t ws_size,
                              hipStream_t stream) {
  const float* x = (const float*)d_in[0];
  const float* y = (const float*)d_in[1];
  const float* W1 = (const float*)d_in[2];
  const float* b1 = (const float*)d_in[3];
  const float* W2 = (const float*)d_in[4];
  const float* b2 = (const float*)d_in[5];
  const float* Wb1 = (const float*)d_in[6];
  const float* bb1 = (const float*)d_in[7];
  const float* Wb2 = (const float*)d_in[8];
  const float* bb2 = (const float*)d_in[9];
  const float* Wc1 = (const float*)d_in[10];
  const float* bc1 = (const float*)d_in[11];
  const float* Wc2 = (const float*)d_in[12];
  const float* bc2 = (const float*)d_in[13];
  const float* meanp = (const float*)d_in[14];
  const float* varp = (const float*)d_in[15];

  float* z = (float*)d_out;
  float* jac = z + (size_t)NS * NXD;

  char* ws = (char*)d_ws;
  __hip_bfloat16* W12T = (__hip_bfloat16*)ws;                        // 4 MB
  __hip_bfloat16* Mb = (__hip_bfloat16*)(ws + (4ull << 20));         // 32 MB
  float* wts = (float*)(ws + (36ull << 20));                         // 2 MB
  // bw (18 KB) lives at the START of the Mb region: branch reads it before
  // moe_kernel writes Mb, so no extra workspace is consumed.
  float* bw = (float*)(ws + (4ull << 20));

  prep_w12<<<dim3(8192), dim3(256), 0, stream>>>(W1, W2, W12T);
  prep_branchw<<<dim3(1), dim3(256), 0, stream>>>(Wb1, Wc1, Wc2, b2, bw);
  branch_kernel<<<dim3(512), dim3(256), 0, stream>>>(
      x, y, bw, Wb2, bb1, bb2, bc1, bc2, meanp, varp, wts, z);
  moe_kernel<<<dim3(4096), dim3(256), 0, stream>>>(x, W1, b1, W2, wts, Mb, z);
  jac_gemm<<<dim3(32, 256), dim3(256), 0, stream>>>(Mb, W12T, jac);
}